// Round 1
// baseline (191.770 us; speedup 1.0000x reference)
//
#include <hip/hip_runtime.h>
#include <cmath>

#define NA 8400
#define NC 80
#define BS 16
#define NMAX 64
#define NWORDS 132   // ceil(8400/64)
#define TOPKK 13
#define CEPS 1e-9f
#define PIF 3.14159265358979323846f

// d_out layout (float32, concatenated):
//   target_labels  : [0,           134400)
//   target_circles : [134400,      537600)
//   target_scores  : [537600,      11289600)
//   fg_mask        : [11289600,    11424000)
//   target_gt_idx  : [11424000,    11558400)
#define OFF_LABELS  0
#define OFF_CIRCLES 134400
#define OFF_SCORES  537600
#define OFF_FG      11289600
#define OFF_TGI     11424000

__device__ __forceinline__ float circle_iou_dev(float gx, float gy, float r1,
                                                float px, float py, float r2) {
    float dx = gx - px, dy = gy - py;
    float d = sqrtf(dx * dx + dy * dy + CEPS);
    float a1 = PIF * r1 * r1, a2 = PIF * r2 * r2;
    float d2 = d * d;
    float c1 = (d2 + r1 * r1 - r2 * r2) / (2.0f * d * r1 + CEPS);
    float c2 = (d2 + r2 * r2 - r1 * r1) / (2.0f * d * r2 + CEPS);
    c1 = fminf(fmaxf(c1, -1.0f), 1.0f);
    c2 = fminf(fmaxf(c2, -1.0f), 1.0f);
    float tri = fmaxf((r1 + r2 - d) * (d + r1 - r2) * (d - r1 + r2) * (d + r1 + r2), 0.0f);
    float lens = r1 * r1 * acosf(c1) + r2 * r2 * acosf(c2) - 0.5f * sqrtf(tri);
    float inter;
    if (d >= r1 + r2)            inter = 0.0f;
    else if (d <= fabsf(r1 - r2)) { float rm = fminf(r1, r2); inter = PIF * rm * rm; }
    else                          inter = lens;
    return inter / (a1 + a2 - inter + CEPS);
}

// K1: one block per (b, j). Compute align row in LDS, top-13 with stable
// tie-break, emit mask_pos bitmask row (topk AND in_gt). Zero pos arrays.
__global__ __launch_bounds__(256) void k1_topk(
    const float* __restrict__ pd_scores, const float* __restrict__ pd_circles,
    const float* __restrict__ anc, const int* __restrict__ gt_labels,
    const float* __restrict__ gt_bboxes, const float* __restrict__ mask_gt,
    unsigned long long* __restrict__ maskbits,
    unsigned int* __restrict__ posal, unsigned int* __restrict__ posov)
{
    __shared__ float s_align[NA];
    __shared__ unsigned long long s_ingt[NWORDS];
    __shared__ unsigned long long s_sel[NWORDS];
    __shared__ float s_redv[4];
    __shared__ int   s_redi[4];

    const int row = blockIdx.x;        // b*64 + j
    const int b   = row >> 6;
    const int t   = threadIdx.x;
    const int lane = t & 63, wv = t >> 6;

    if (t == 0) { posal[row] = 0u; posov[row] = 0u; }

    const float mg = mask_gt[row];
    if (mg <= 0.0f) {
        for (int w = t; w < NWORDS; w += 256)
            maskbits[(size_t)row * NWORDS + w] = 0ull;
        return;
    }

    const float gx = gt_bboxes[row * 3 + 0];
    const float gy = gt_bboxes[row * 3 + 1];
    const float gr = gt_bboxes[row * 3 + 2];
    int lab = gt_labels[row];
    lab = min(max(lab, 0), NC - 1);

    // main loop: 33 iterations of 256 threads covers 8400 (+ pad)
    for (int k = 0; k < 33; ++k) {
        int a = k * 256 + t;
        bool in_gt = false;
        if (a < NA) {
            float ax = anc[2 * a], ay = anc[2 * a + 1];
            float dx = gx - ax, dy = gy - ay;
            float dn = sqrtf(dx * dx + dy * dy);   // linalg.norm (no eps)
            in_gt = (dn <= gr);
            float align = 0.0f;
            if (in_gt) {
                float px = pd_circles[(size_t)(b * NA + a) * 3 + 0];
                float py = pd_circles[(size_t)(b * NA + a) * 3 + 1];
                float pr = pd_circles[(size_t)(b * NA + a) * 3 + 2];
                float iou = circle_iou_dev(gx, gy, gr, px, py, pr);
                float sc  = pd_scores[((size_t)b * NA + a) * NC + lab];
                float o2 = iou * iou;
                align = sc * (o2 * o2 * o2);
            }
            s_align[a] = align;
        }
        unsigned long long m = __ballot(in_gt);
        if (lane == 0) s_ingt[k * 4 + wv] = m;
    }
    for (int w = t; w < NWORDS; w += 256) s_sel[w] = 0ull;
    __syncthreads();

    // 13 iterations of block-wide argmax (value desc, index asc tie-break)
    for (int it = 0; it < TOPKK; ++it) {
        float bv = -2.0f; int bi = NA;
        for (int a = t; a < NA; a += 256) {
            float v = s_align[a];
            if (v > bv) { bv = v; bi = a; }      // ascending a: first max kept
        }
        for (int off = 32; off > 0; off >>= 1) {
            float ov = __shfl_down(bv, off);
            int   oi = __shfl_down(bi, off);
            if (ov > bv || (ov == bv && oi < bi)) { bv = ov; bi = oi; }
        }
        if (lane == 0) { s_redv[wv] = bv; s_redi[wv] = bi; }
        __syncthreads();
        if (t == 0) {
            float vb = s_redv[0]; int ib = s_redi[0];
            for (int w2 = 1; w2 < 4; ++w2)
                if (s_redv[w2] > vb || (s_redv[w2] == vb && s_redi[w2] < ib))
                    { vb = s_redv[w2]; ib = s_redi[w2]; }
            s_sel[ib >> 6] |= (1ull << (ib & 63));
            s_align[ib] = -1.0f;
        }
        __syncthreads();
    }

    for (int w = t; w < NWORDS; w += 256)
        maskbits[(size_t)row * NWORDS + w] = (s_sel[w] & s_ingt[w]);
}

// K2: one thread per (b, a). Count bits over j, resolve contested anchors by
// overlap argmax (first-max), write labels/circles/fg/tgi, accumulate
// pos_align/pos_overlaps via atomicMax on uint-reinterpreted non-neg floats.
__global__ __launch_bounds__(256) void k2_resolve(
    const float* __restrict__ pd_scores, const float* __restrict__ pd_circles,
    const float* __restrict__ anc, const int* __restrict__ gt_labels,
    const float* __restrict__ gt_bboxes, const float* __restrict__ mask_gt,
    const unsigned long long* __restrict__ maskbits,
    float* __restrict__ out, int* __restrict__ tgiE, float* __restrict__ alignv,
    unsigned int* __restrict__ posal, unsigned int* __restrict__ posov)
{
    const int idx = blockIdx.x * 256 + threadIdx.x;   // < 134400
    const int b = idx / NA;
    const int a = idx - b * NA;
    const int word = a >> 6, bit = a & 63;

    const unsigned long long* mrow = maskbits + (size_t)b * NMAX * NWORDS + word;
    int cnt = 0, firstj = -1;
    for (int j = 0; j < NMAX; ++j) {
        int bv = (int)((mrow[j * NWORDS] >> bit) & 1ull);
        cnt += bv;
        if (bv && firstj < 0) firstj = j;
    }

    int tgi = 0, fg = 0;
    if (cnt == 1) { fg = 1; tgi = firstj; }
    else if (cnt > 1) {
        fg = 1;
        float px = pd_circles[(size_t)idx * 3 + 0];
        float py = pd_circles[(size_t)idx * 3 + 1];
        float pr = pd_circles[(size_t)idx * 3 + 2];
        float ax = anc[2 * a], ay = anc[2 * a + 1];
        float bo = -1.0f; int bj = 0;
        for (int j = 0; j < NMAX; ++j) {
            float mgv = mask_gt[b * NMAX + j];
            float gx = gt_bboxes[(b * NMAX + j) * 3 + 0];
            float gy = gt_bboxes[(b * NMAX + j) * 3 + 1];
            float gr = gt_bboxes[(b * NMAX + j) * 3 + 2];
            float ovj = 0.0f;
            if (mgv > 0.0f) {
                float dx = gx - ax, dy = gy - ay;
                float dn = sqrtf(dx * dx + dy * dy);
                if (dn <= gr) ovj = circle_iou_dev(gx, gy, gr, px, py, pr);
            }
            if (ovj > bo) { bo = ovj; bj = j; }  // strict >: numpy first-max
        }
        tgi = bj;
    }

    const int gl = gt_labels[b * NMAX + tgi];
    const float gx = gt_bboxes[(b * NMAX + tgi) * 3 + 0];
    const float gy = gt_bboxes[(b * NMAX + tgi) * 3 + 1];
    const float gr = gt_bboxes[(b * NMAX + tgi) * 3 + 2];

    out[OFF_LABELS + idx] = (float)max(gl, 0);
    out[OFF_CIRCLES + (size_t)idx * 3 + 0] = gx;
    out[OFF_CIRCLES + (size_t)idx * 3 + 1] = gy;
    out[OFF_CIRCLES + (size_t)idx * 3 + 2] = gr;
    out[OFF_FG + idx]  = (float)fg;
    out[OFF_TGI + idx] = (float)tgi;
    tgiE[idx] = fg ? tgi : -1;

    float alg = 0.0f;
    if (fg) {
        float ovv = 0.0f;
        float mgv = mask_gt[b * NMAX + tgi];
        float ax = anc[2 * a], ay = anc[2 * a + 1];
        float dx = gx - ax, dy = gy - ay;
        float dn = sqrtf(dx * dx + dy * dy);
        if (mgv > 0.0f && dn <= gr) {
            float px = pd_circles[(size_t)idx * 3 + 0];
            float py = pd_circles[(size_t)idx * 3 + 1];
            float pr = pd_circles[(size_t)idx * 3 + 2];
            float iou = circle_iou_dev(gx, gy, gr, px, py, pr);
            int lab = min(max(gl, 0), NC - 1);
            float sc = pd_scores[((size_t)b * NA + a) * NC + lab];
            ovv = iou;
            float o2 = iou * iou;
            alg = sc * (o2 * o2 * o2);
        }
        atomicMax(&posal[b * NMAX + tgi], __float_as_uint(alg));
        atomicMax(&posov[b * NMAX + tgi], __float_as_uint(ovv));
    }
    alignv[idx] = alg;
}

// K3: zero-fill target_scores (10,752,000 floats = 2,688,000 float4)
__global__ __launch_bounds__(256) void k3_zero(float4* __restrict__ p, int n4)
{
    int i = blockIdx.x * 256 + threadIdx.x;
    if (i < n4) p[i] = make_float4(0.f, 0.f, 0.f, 0.f);
}

// K4: scatter norm into target_scores[b, a, label] for fg anchors
__global__ __launch_bounds__(256) void k4_scatter(
    const int* __restrict__ tgiE, const float* __restrict__ alignv,
    const unsigned int* __restrict__ posal, const unsigned int* __restrict__ posov,
    const int* __restrict__ gt_labels, float* __restrict__ out)
{
    int idx = blockIdx.x * 256 + threadIdx.x;   // < 134400
    int tg = tgiE[idx];
    if (tg < 0) return;
    int b = idx / NA;
    float pa = __uint_as_float(posal[b * NMAX + tg]);
    float po = __uint_as_float(posov[b * NMAX + tg]);
    float norm = alignv[idx] * po / (pa + CEPS);
    int lab = max(gt_labels[b * NMAX + tg], 0);
    out[OFF_SCORES + (size_t)idx * NC + lab] = norm;
}

extern "C" void kernel_launch(void* const* d_in, const int* in_sizes, int n_in,
                              void* d_out, int out_size, void* d_ws, size_t ws_size,
                              hipStream_t stream) {
    const float* pd_scores  = (const float*)d_in[0];
    const float* pd_circles = (const float*)d_in[1];
    const float* anc        = (const float*)d_in[2];
    const int*   gt_labels  = (const int*)d_in[3];
    const float* gt_bboxes  = (const float*)d_in[4];
    const float* mask_gt    = (const float*)d_in[5];
    float* out = (float*)d_out;

    char* ws = (char*)d_ws;
    unsigned long long* maskbits = (unsigned long long*)ws;          // 1,081,344 B
    unsigned int* posal = (unsigned int*)(ws + 1081344);             // 4 KB slot
    unsigned int* posov = (unsigned int*)(ws + 1081344 + 4096);      // 4 KB slot
    int*   tgiE   = (int*)(ws + 1081344 + 8192);                     // 537,600 B
    float* alignv = (float*)(ws + 1081344 + 8192 + 537600);          // 537,600 B

    k1_topk<<<BS * NMAX, 256, 0, stream>>>(pd_scores, pd_circles, anc, gt_labels,
                                           gt_bboxes, mask_gt, maskbits, posal, posov);
    k2_resolve<<<(BS * NA) / 256, 256, 0, stream>>>(pd_scores, pd_circles, anc,
                                                    gt_labels, gt_bboxes, mask_gt,
                                                    maskbits, out, tgiE, alignv,
                                                    posal, posov);
    k3_zero<<<(BS * NA * NC / 4 + 255) / 256, 256, 0, stream>>>(
        (float4*)(out + OFF_SCORES), BS * NA * NC / 4);
    k4_scatter<<<(BS * NA) / 256, 256, 0, stream>>>(tgiE, alignv, posal, posov,
                                                    gt_labels, out);
}

// Round 2
// 165.325 us; speedup vs baseline: 1.1600x; 1.1600x over previous
//
#include <hip/hip_runtime.h>
#include <cmath>

#define NA 8400
#define NC 80
#define BS 16
#define NMAX 64
#define TOPKK 13
#define CAP 768
#define CEPS 1e-9f
#define PIF 3.14159265358979323846f

// d_out layout (float32, concatenated)
#define OFF_LABELS  0
#define OFF_CIRCLES 134400
#define OFF_SCORES  537600
#define OFF_FG      11289600
#define OFF_TGI     11424000

// workspace layout (bytes)
//   colbits : [0, 1075200)           134400 x u64  (bit j set => mask_pos[b,j,a]=1)
//   posal   : [1075200, 1079296)     1024 x u32
//   posov   : [1079296, 1083392)     1024 x u32
//   tgiE    : [1083392, 1620992)     134400 x i32
//   alignv  : [1620992, 2158592)     134400 x f32
#define WS_POSAL   1075200
#define WS_POSOV   1079296
#define WS_TGI     1083392
#define WS_ALIGN   1620992
#define ZERO1_F4   67712      // (colbits+posal+posov)/16
#define ZERO2_F4   2688000    // target_scores floats /4

__device__ __forceinline__ float circle_iou_dev(float gx, float gy, float r1,
                                                float px, float py, float r2) {
    float dx = gx - px, dy = gy - py;
    float d = sqrtf(dx * dx + dy * dy + CEPS);
    float a1 = PIF * r1 * r1, a2 = PIF * r2 * r2;
    float d2 = d * d;
    float c1 = (d2 + r1 * r1 - r2 * r2) / (2.0f * d * r1 + CEPS);
    float c2 = (d2 + r2 * r2 - r1 * r1) / (2.0f * d * r2 + CEPS);
    c1 = fminf(fmaxf(c1, -1.0f), 1.0f);
    c2 = fminf(fmaxf(c2, -1.0f), 1.0f);
    float tri = fmaxf((r1 + r2 - d) * (d + r1 - r2) * (d - r1 + r2) * (d + r1 + r2), 0.0f);
    float lens = r1 * r1 * acosf(c1) + r2 * r2 * acosf(c2) - 0.5f * sqrtf(tri);
    float inter;
    if (d >= r1 + r2)             inter = 0.0f;
    else if (d <= fabsf(r1 - r2)) { float rm = fminf(r1, r2); inter = PIF * rm * rm; }
    else                          inter = lens;
    return inter / (a1 + a2 - inter + CEPS);
}

// K0: zero colbits+posal+posov (ws) and target_scores (out)
__global__ __launch_bounds__(256) void k0_zero(float4* __restrict__ wsz,
                                               float4* __restrict__ scores)
{
    int i = blockIdx.x * 256 + threadIdx.x;
    if (i < ZERO2_F4) scores[i] = make_float4(0.f, 0.f, 0.f, 0.f);
    else { int k = i - ZERO2_F4; if (k < ZERO1_F4) wsz[k] = make_float4(0.f, 0.f, 0.f, 0.f); }
}

// K1: one block per (b, j). Compact in-gt candidates, dense align compute,
// 13-pass argmax over compacted list, zero-filler per reference top_k tie
// semantics, emit selected-and-in-gt bits into per-anchor GT columns.
__global__ __launch_bounds__(256) void k1_topk(
    const float* __restrict__ pd_scores, const float* __restrict__ pd_circles,
    const float* __restrict__ anc, const int* __restrict__ gt_labels,
    const float* __restrict__ gt_bboxes, const float* __restrict__ mask_gt,
    unsigned long long* __restrict__ colbits)
{
    __shared__ int   s_cidx[CAP];
    __shared__ float s_cval[CAP];
    __shared__ float s_low[64];            // align of anchors 0..63 (0 default)
    __shared__ unsigned long long s_ingt0; // in-gt bits for anchors 0..63
    __shared__ int   s_ncand, s_nsel, s_done;
    __shared__ float s_redv[4];
    __shared__ int   s_redi[4], s_redc[4];
    __shared__ int   s_sel[16];

    const int row = blockIdx.x;            // b*64 + j
    const int b = row >> 6, j = row & 63;
    const int t = threadIdx.x;
    const int lane = t & 63, wv = t >> 6;

    if (mask_gt[row] <= 0.0f) return;      // colbits pre-zeroed by K0

    const float gx = gt_bboxes[row * 3 + 0];
    const float gy = gt_bboxes[row * 3 + 1];
    const float gr = gt_bboxes[row * 3 + 2];
    int lab = gt_labels[row];
    lab = min(max(lab, 0), NC - 1);

    if (t == 0) { s_ncand = 0; s_nsel = 0; s_done = 0; }
    if (t < 64) s_low[t] = 0.0f;
    __syncthreads();

    // phase A: distance scan + compaction
    for (int k = 0; k < 33; ++k) {
        int a = k * 256 + t;
        bool in_gt = false;
        if (a < NA) {
            float ax = anc[2 * a], ay = anc[2 * a + 1];
            float dx = gx - ax, dy = gy - ay;
            in_gt = (sqrtf(dx * dx + dy * dy) <= gr);
        }
        if (in_gt) {
            int p = atomicAdd(&s_ncand, 1);
            if (p < CAP) s_cidx[p] = a;
        }
        if (k == 0 && wv == 0) {
            unsigned long long m = __ballot(in_gt);
            if (lane == 0) s_ingt0 = m;
        }
    }
    __syncthreads();
    const int n = min(s_ncand, CAP);

    // phase B: dense align compute over candidates
    for (int c = t; c < n; c += 256) {
        int a = s_cidx[c];
        size_t pi = (size_t)(b * NA + a);
        float px = pd_circles[pi * 3 + 0];
        float py = pd_circles[pi * 3 + 1];
        float pr = pd_circles[pi * 3 + 2];
        float iou = circle_iou_dev(gx, gy, gr, px, py, pr);
        float sc  = pd_scores[pi * NC + lab];
        float o2 = iou * iou;
        float v = sc * (o2 * o2 * o2);
        s_cval[c] = v;
        if (a < 64) s_low[a] = v;
    }
    __syncthreads();

    // phase C: 13-pass argmax (value desc, anchor-idx asc)
    for (int it = 0; it < TOPKK; ++it) {
        float bv = -1.0f; int bi = 1 << 30, bc = -1;
        for (int c = t; c < n; c += 256) {
            float v = s_cval[c]; int a = s_cidx[c];
            if (v > bv || (v == bv && a < bi)) { bv = v; bi = a; bc = c; }
        }
        for (int off = 32; off > 0; off >>= 1) {
            float ov = __shfl_down(bv, off);
            int   oi = __shfl_down(bi, off);
            int   oc = __shfl_down(bc, off);
            if (ov > bv || (ov == bv && oi < bi)) { bv = ov; bi = oi; bc = oc; }
        }
        if (lane == 0) { s_redv[wv] = bv; s_redi[wv] = bi; s_redc[wv] = bc; }
        __syncthreads();
        if (t == 0) {
            float vb = s_redv[0]; int ib = s_redi[0], cb = s_redc[0];
            for (int w = 1; w < 4; ++w)
                if (s_redv[w] > vb || (s_redv[w] == vb && s_redi[w] < ib))
                    { vb = s_redv[w]; ib = s_redi[w]; cb = s_redc[w]; }
            if (vb > 0.0f) { s_sel[s_nsel] = ib; s_nsel++; s_cval[cb] = -1.0f; }
            else s_done = 1;
        }
        __syncthreads();
        if (s_done) break;
    }

    // phase D: zero-filler — reference top_k fills remaining slots with the
    // globally lowest-index zero-valued entries; keep only in-gt ones.
    if (t == 0) {
        int r = TOPKK - s_nsel;
        if (r > 0) {
            for (int idx = 0; idx < 64 && r > 0; ++idx) {
                if (s_low[idx] > 0.0f) continue;   // positive candidate, skip
                r--;                                // consumes a zero slot
                if ((s_ingt0 >> idx) & 1ull) { s_sel[s_nsel] = idx; s_nsel++; }
            }
        }
    }
    __syncthreads();

    // phase E: set bit j in each selected anchor's GT column
    if (t < s_nsel)
        atomicOr(&colbits[(size_t)b * NA + s_sel[t]], 1ull << j);
}

// K2: one thread per (b, a). Coalesced column read; resolve contested anchors
// by overlap argmax (first-max); outputs + pos_align/pos_overlaps atomicMax.
__global__ __launch_bounds__(256) void k2_resolve(
    const float* __restrict__ pd_scores, const float* __restrict__ pd_circles,
    const float* __restrict__ anc, const int* __restrict__ gt_labels,
    const float* __restrict__ gt_bboxes, const float* __restrict__ mask_gt,
    const unsigned long long* __restrict__ colbits,
    float* __restrict__ out, int* __restrict__ tgiE, float* __restrict__ alignv,
    unsigned int* __restrict__ posal, unsigned int* __restrict__ posov)
{
    const int idx = blockIdx.x * 256 + threadIdx.x;   // < 134400
    const int b = idx / NA;
    const int a = idx - b * NA;

    const unsigned long long col = colbits[idx];
    const int cnt = __popcll(col);

    int tgi = 0, fg = 0;
    if (cnt == 1) { fg = 1; tgi = __ffsll((unsigned long long)col) - 1; }
    else if (cnt > 1) {
        fg = 1;
        float px = pd_circles[(size_t)idx * 3 + 0];
        float py = pd_circles[(size_t)idx * 3 + 1];
        float pr = pd_circles[(size_t)idx * 3 + 2];
        float ax = anc[2 * a], ay = anc[2 * a + 1];
        float bo = -1.0f; int bj = 0;
        for (int j = 0; j < NMAX; ++j) {
            float mgv = mask_gt[b * NMAX + j];
            float gx = gt_bboxes[(b * NMAX + j) * 3 + 0];
            float gy = gt_bboxes[(b * NMAX + j) * 3 + 1];
            float gr = gt_bboxes[(b * NMAX + j) * 3 + 2];
            float ovj = 0.0f;
            if (mgv > 0.0f) {
                float dx = gx - ax, dy = gy - ay;
                if (sqrtf(dx * dx + dy * dy) <= gr)
                    ovj = circle_iou_dev(gx, gy, gr, px, py, pr);
            }
            if (ovj > bo) { bo = ovj; bj = j; }  // strict >: first-max
        }
        tgi = bj;
    }

    const int gl = gt_labels[b * NMAX + tgi];
    const float gx = gt_bboxes[(b * NMAX + tgi) * 3 + 0];
    const float gy = gt_bboxes[(b * NMAX + tgi) * 3 + 1];
    const float gr = gt_bboxes[(b * NMAX + tgi) * 3 + 2];

    out[OFF_LABELS + idx] = (float)max(gl, 0);
    out[OFF_CIRCLES + (size_t)idx * 3 + 0] = gx;
    out[OFF_CIRCLES + (size_t)idx * 3 + 1] = gy;
    out[OFF_CIRCLES + (size_t)idx * 3 + 2] = gr;
    out[OFF_FG + idx]  = (float)fg;
    out[OFF_TGI + idx] = (float)tgi;
    tgiE[idx] = fg ? tgi : -1;

    float alg = 0.0f;
    if (fg) {
        float ovv = 0.0f;
        float mgv = mask_gt[b * NMAX + tgi];
        float ax = anc[2 * a], ay = anc[2 * a + 1];
        float dx = gx - ax, dy = gy - ay;
        if (mgv > 0.0f && sqrtf(dx * dx + dy * dy) <= gr) {
            float px = pd_circles[(size_t)idx * 3 + 0];
            float py = pd_circles[(size_t)idx * 3 + 1];
            float pr = pd_circles[(size_t)idx * 3 + 2];
            float iou = circle_iou_dev(gx, gy, gr, px, py, pr);
            int lab = min(max(gl, 0), NC - 1);
            float sc = pd_scores[((size_t)b * NA + a) * NC + lab];
            ovv = iou;
            float o2 = iou * iou;
            alg = sc * (o2 * o2 * o2);
        }
        atomicMax(&posal[b * NMAX + tgi], __float_as_uint(alg));
        atomicMax(&posov[b * NMAX + tgi], __float_as_uint(ovv));
    }
    alignv[idx] = alg;
}

// K4: scatter norm into target_scores[b, a, label] for fg anchors
__global__ __launch_bounds__(256) void k4_scatter(
    const int* __restrict__ tgiE, const float* __restrict__ alignv,
    const unsigned int* __restrict__ posal, const unsigned int* __restrict__ posov,
    const int* __restrict__ gt_labels, float* __restrict__ out)
{
    int idx = blockIdx.x * 256 + threadIdx.x;   // < 134400
    int tg = tgiE[idx];
    if (tg < 0) return;
    int b = idx / NA;
    float pa = __uint_as_float(posal[b * NMAX + tg]);
    float po = __uint_as_float(posov[b * NMAX + tg]);
    float norm = alignv[idx] * po / (pa + CEPS);
    int lab = max(gt_labels[b * NMAX + tg], 0);
    out[OFF_SCORES + (size_t)idx * NC + lab] = norm;
}

extern "C" void kernel_launch(void* const* d_in, const int* in_sizes, int n_in,
                              void* d_out, int out_size, void* d_ws, size_t ws_size,
                              hipStream_t stream) {
    const float* pd_scores  = (const float*)d_in[0];
    const float* pd_circles = (const float*)d_in[1];
    const float* anc        = (const float*)d_in[2];
    const int*   gt_labels  = (const int*)d_in[3];
    const float* gt_bboxes  = (const float*)d_in[4];
    const float* mask_gt    = (const float*)d_in[5];
    float* out = (float*)d_out;

    char* ws = (char*)d_ws;
    unsigned long long* colbits = (unsigned long long*)ws;
    unsigned int* posal = (unsigned int*)(ws + WS_POSAL);
    unsigned int* posov = (unsigned int*)(ws + WS_POSOV);
    int*   tgiE   = (int*)(ws + WS_TGI);
    float* alignv = (float*)(ws + WS_ALIGN);

    const int nz = ZERO2_F4 + ZERO1_F4;
    k0_zero<<<(nz + 255) / 256, 256, 0, stream>>>((float4*)ws,
                                                  (float4*)(out + OFF_SCORES));
    k1_topk<<<BS * NMAX, 256, 0, stream>>>(pd_scores, pd_circles, anc, gt_labels,
                                           gt_bboxes, mask_gt, colbits);
    k2_resolve<<<(BS * NA) / 256, 256, 0, stream>>>(pd_scores, pd_circles, anc,
                                                    gt_labels, gt_bboxes, mask_gt,
                                                    colbits, out, tgiE, alignv,
                                                    posal, posov);
    k4_scatter<<<(BS * NA) / 256, 256, 0, stream>>>(tgiE, alignv, posal, posov,
                                                    gt_labels, out);
}